// Round 9
// baseline (81.661 us; speedup 1.0000x reference)
//
#include <hip/hip_runtime.h>
#include <hip/hip_bf16.h>
#include <stdint.h>

#define B_   32
#define N_   128
#define E_   8192
#define IMG_ 2048
#define H_   128

typedef __attribute__((ext_vector_type(8))) short bf16x8;
typedef __attribute__((ext_vector_type(4))) float f32x4;

__device__ inline uint16_t f2bf(float x) {
    uint32_t u = __float_as_uint(x);
    uint32_t r = (u + 0x7FFFu + ((u >> 16) & 1u)) >> 16;
    return (uint16_t)r;
}
__device__ inline float bf2f(short x) {
    return __uint_as_float(((uint32_t)(uint16_t)x) << 16);
}

// ---------------------------------------------------------------------------
// Persistent fused kernel. 256 blocks x 1024 thr, 128 KB LDS -> 1 block/CU,
// all blocks co-resident (r6-verified skeleton).
//   blocks 224..255: prep slices -> release flags[0]
//   all: A-stage -> spin prep -> node GEMM/reduce/epilogue/proj -> release
//        flags[1] -> ONE global wait -> free-running ILP edge phase with
//        plain cached stores (NT proven -35us; barrier-gated loop removed).
// ---------------------------------------------------------------------------
__global__ __launch_bounds__(1024) void fused_kernel(
    const float* __restrict__ img_feat,
    const float* __restrict__ img_loc,
    const int* __restrict__ edge_src,
    const int* __restrict__ edge_dst,
    const float* __restrict__ W_img,
    const float* __restrict__ b_img,
    const float* __restrict__ W_loc,
    const float* __restrict__ b_loc,
    const float* __restrict__ W_rel,
    const float* __restrict__ b_rel,
    float* __restrict__ out_node,
    float* __restrict__ out_edge,
    uint16_t* __restrict__ Wt_img,
    uint16_t* __restrict__ Wt_rel,
    uint16_t* __restrict__ proj,
    int* flags) {
    __shared__ __align__(16) char lds_raw[131072];
    float (*red)[16][128] = (float (*)[16][128])lds_raw;   // aliases A-tile
    uint16_t (*imgb)[136] = (uint16_t (*)[136])lds_raw;    // aliases too
    float (*tT)[129] = (float (*)[129])lds_raw;            // prep transpose

    int bid = blockIdx.x;
    int tid = threadIdx.x;
    int w  = tid >> 6;       // wave 0..15 = K-slice
    int l  = tid & 63;
    int lr = l & 15;
    int kq = l >> 4;

    // ---- prep phase (blocks 224..255 only; block-uniform branch) ----
    if (bid >= 224) {
        int pb = bid - 224;              // 0..31
        int k0 = pb * 64;
        const float* src = W_img + (size_t)k0 * H_;
        #pragma unroll
        for (int it = 0; it < 8; it++) {
            int idx = it * 1024 + tid;   // [64 k][128 c], coalesced
            tT[idx >> 7][idx & 127] = src[idx];
        }
        __syncthreads();
        {
            int c = tid >> 3, kh = (tid & 7) * 8;
            uint16_t* dst = Wt_img + (size_t)c * IMG_ + k0 + kh;
            #pragma unroll
            for (int j = 0; j < 8; j++) dst[j] = f2bf(tT[kh + j][c]);
        }
        {
            int t2 = pb * 1024 + tid;    // 0..32767
            int c2 = t2 >> 8, k2 = t2 & 255;
            Wt_rel[t2] = f2bf(W_rel[k2 * H_ + c2]);
        }
        __syncthreads();   // drains stores + LDS reuse safety
        if (tid == 0)
            __hip_atomic_fetch_add(&flags[0], 1, __ATOMIC_RELEASE,
                                   __HIP_MEMORY_SCOPE_AGENT);
    }

    // ---- A-stage: 8 x 16B per thread, linear LDS dest, swizzled source ----
    const char* gA = (const char*)(img_feat + (size_t)bid * 16 * IMG_);
    #pragma unroll
    for (int r = 0; r < 8; r++) {
        int L = r * 16384 + tid * 16;
        int row = L >> 13;
        int koff = L & 8191;
        int gsrc = row * 8192 + (koff ^ ((row & 7) << 4));
        __builtin_amdgcn_global_load_lds(
            (const __attribute__((address_space(1))) void*)(gA + gsrc),
            (__attribute__((address_space(3))) void*)(lds_raw + L), 16, 0, 0);
    }

    // ---- wait for ALL prep slices ----
    if (tid == 0) {
        while (__hip_atomic_load(&flags[0], __ATOMIC_RELAXED,
                                 __HIP_MEMORY_SCOPE_AGENT) < 32) {}
        (void)__hip_atomic_load(&flags[0], __ATOMIC_ACQUIRE,
                                __HIP_MEMORY_SCOPE_AGENT);
    }
    __syncthreads();   // joins spin; A-stage loads drained per-wave here

    // ---- node GEMM (K-slice per wave) ----
    int kbase = w * 128 + kq * 8;
    bf16x8 bcur[8];
    #pragma unroll
    for (int n = 0; n < 8; n++)
        bcur[n] = *(const bf16x8*)(Wt_img + (size_t)(n * 16 + lr) * IMG_ + kbase);

    f32x4 acc[8];
    #pragma unroll
    for (int n = 0; n < 8; n++) acc[n] = (f32x4){0.f, 0.f, 0.f, 0.f};
    int sw = (lr & 7) << 4;
    #pragma unroll
    for (int ks = 0; ks < 4; ks++) {
        int koffb = w * 512 + ks * 128 + kq * 32;
        float4 a0 = *(const float4*)(lds_raw + (size_t)lr * 8192 + (koffb ^ sw));
        float4 a1 = *(const float4*)(lds_raw + (size_t)lr * 8192 + ((koffb + 16) ^ sw));
        bf16x8 bn[8];
        if (ks < 3) {
            int kn = kbase + (ks + 1) * 32;
            #pragma unroll
            for (int n = 0; n < 8; n++)
                bn[n] = *(const bf16x8*)(Wt_img + (size_t)(n * 16 + lr) * IMG_ + kn);
        }
        bf16x8 af;
        af[0] = (short)f2bf(a0.x); af[1] = (short)f2bf(a0.y);
        af[2] = (short)f2bf(a0.z); af[3] = (short)f2bf(a0.w);
        af[4] = (short)f2bf(a1.x); af[5] = (short)f2bf(a1.y);
        af[6] = (short)f2bf(a1.z); af[7] = (short)f2bf(a1.w);
        #pragma unroll
        for (int n = 0; n < 8; n++)
            acc[n] = __builtin_amdgcn_mfma_f32_16x16x32_bf16(af, bcur[n], acc[n], 0, 0, 0);
        if (ks < 3) {
            #pragma unroll
            for (int n = 0; n < 8; n++) bcur[n] = bn[n];
        }
    }
    __syncthreads();   // all A-tile reads done before red overwrites it

    // ---- partial dump ----
    #pragma unroll
    for (int n = 0; n < 8; n++)
        #pragma unroll
        for (int r = 0; r < 4; r++)
            red[w][kq * 4 + r][n * 16 + lr] = acc[n][r];
    __syncthreads();

    // ---- reduce + epilogue ----
    int row0 = tid >> 7, col = tid & 127;
    int row1 = row0 + 8;
    float s0 = 0.f, s1 = 0.f;
    #pragma unroll
    for (int ww = 0; ww < 16; ww++) {
        s0 += red[ww][row0][col];
        s1 += red[ww][row1][col];
    }
    __syncthreads();   // red reads done before imgb overwrites

    {
        float bi = b_img[col];
        float bl = b_loc[col];
        float wl[5];
        #pragma unroll
        for (int j = 0; j < 5; j++) wl[j] = W_loc[j * H_ + col];
        float img0 = s0 + bi, img1 = s1 + bi;
        int g0 = bid * 16 + row0, g1 = bid * 16 + row1;
        const float* lc0 = img_loc + g0 * 5;
        const float* lc1 = img_loc + g1 * 5;
        float loc0 = bl, loc1 = bl;
        #pragma unroll
        for (int j = 0; j < 5; j++) { loc0 += lc0[j] * wl[j]; loc1 += lc1[j] * wl[j]; }
        out_node[(size_t)g0 * H_ + col] = img0 + loc0;
        out_node[(size_t)g1 * H_ + col] = img1 + loc1;
        imgb[row0][col] = f2bf(img0);
        imgb[row1][col] = f2bf(img1);
    }
    __syncthreads();   // imgb visible

    // ---- proj GEMM (K=128, 256 cols; wave w -> cols w*16..w*16+15) ----
    {
        int kl = kq * 8;
        int cp = w * 16 + lr;
        const uint16_t* bbase = (cp < 128)
            ? (Wt_rel + (size_t)cp * 256)
            : (Wt_rel + (size_t)(cp - 128) * 256 + 128);
        f32x4 pacc = (f32x4){0.f, 0.f, 0.f, 0.f};
        #pragma unroll
        for (int ks = 0; ks < 4; ks++) {
            int k = ks * 32 + kl;
            bf16x8 af = *(const bf16x8*)(&imgb[lr][k]);
            bf16x8 bf = *(const bf16x8*)(bbase + k);
            pacc = __builtin_amdgcn_mfma_f32_16x16x32_bf16(af, bf, pacc, 0, 0, 0);
        }
        float brel = (cp < 128) ? b_rel[cp] : 0.f;
        #pragma unroll
        for (int r = 0; r < 4; r++) {
            int grow = bid * 16 + kq * 4 + r;
            proj[(size_t)grow * 256 + cp] = f2bf(pacc[r] + brel);
        }
    }
    __syncthreads();   // drains proj stores (vmcnt0 at barrier)
    if (tid == 0)
        __hip_atomic_fetch_add(&flags[1], 1, __ATOMIC_RELEASE,
                               __HIP_MEMORY_SCOPE_AGENT);

    // ---- ONE global wait: all proj written, then free-running edge ----
    if (tid == 0) {
        while (__hip_atomic_load(&flags[1], __ATOMIC_RELAXED,
                                 __HIP_MEMORY_SCOPE_AGENT) < 256) {}
        (void)__hip_atomic_load(&flags[1], __ATOMIC_ACQUIRE,
                                __HIP_MEMORY_SCOPE_AGENT);
    }
    __syncthreads();

    // ---- edge phase (r4 structure): e,c,s,d invariant; b = bstart + 2*it ----
    int t = bid * 1024 + tid;          // 0..262143
    int oct = t & 131071;
    int bstart = t >> 17;              // 0 or 1
    int e = oct >> 4, c = (oct & 15) << 3;
    int s = edge_src[e], d = edge_dst[e];
    const uint16_t* ps = proj + (size_t)s * 256 + c;
    const uint16_t* pd = proj + (size_t)d * 256 + 128 + c;
    float* op = out_edge + (size_t)e * H_ + c;
    const size_t PB = (size_t)N_ * 256;    // proj elems per batch
    const size_t OB = (size_t)E_ * H_;     // out floats per batch

    #pragma unroll
    for (int h = 0; h < 4; h++) {
        bf16x8 av[4], bv[4];
        #pragma unroll
        for (int i = 0; i < 4; i++) {
            int b = bstart + 2 * (h * 4 + i);
            av[i] = *(const bf16x8*)(ps + (size_t)b * PB);
            bv[i] = *(const bf16x8*)(pd + (size_t)b * PB);
        }
        #pragma unroll
        for (int i = 0; i < 4; i++) {
            int b = bstart + 2 * (h * 4 + i);
            f32x4 o0, o1;
            o0[0] = bf2f(av[i][0]) + bf2f(bv[i][0]);
            o0[1] = bf2f(av[i][1]) + bf2f(bv[i][1]);
            o0[2] = bf2f(av[i][2]) + bf2f(bv[i][2]);
            o0[3] = bf2f(av[i][3]) + bf2f(bv[i][3]);
            o1[0] = bf2f(av[i][4]) + bf2f(bv[i][4]);
            o1[1] = bf2f(av[i][5]) + bf2f(bv[i][5]);
            o1[2] = bf2f(av[i][6]) + bf2f(bv[i][6]);
            o1[3] = bf2f(av[i][7]) + bf2f(bv[i][7]);
            float* dst = op + (size_t)b * OB;
            *(f32x4*)dst = o0;
            *(f32x4*)(dst + 4) = o1;
        }
    }
}

// ---------------------------------------------------------------------------
extern "C" void kernel_launch(void* const* d_in, const int* in_sizes, int n_in,
                              void* d_out, int out_size, void* d_ws, size_t ws_size,
                              hipStream_t stream) {
    const float* img_feat = (const float*)d_in[0];
    const float* img_loc  = (const float*)d_in[1];
    const int*   edge_src = (const int*)d_in[2];
    const int*   edge_dst = (const int*)d_in[3];
    const float* W_img    = (const float*)d_in[4];
    const float* b_img    = (const float*)d_in[5];
    const float* W_loc    = (const float*)d_in[6];
    const float* b_loc    = (const float*)d_in[7];
    const float* W_rel    = (const float*)d_in[8];
    const float* b_rel    = (const float*)d_in[9];

    float* out_node = (float*)d_out;                       // [B,N,H]
    float* out_edge = out_node + (size_t)B_ * N_ * H_;     // [B,E,H]

    // ws: Wt_img 512K | Wt_rel 64K | proj 2M | flags
    char* ws = (char*)d_ws;
    uint16_t* Wt_img = (uint16_t*)ws;
    uint16_t* Wt_rel = (uint16_t*)(ws + 524288);
    uint16_t* proj   = (uint16_t*)(ws + 589824);
    int*      flags  = (int*)(ws + 589824 + 2097152);

    (void)hipMemsetAsync(flags, 0, 256, stream);

    fused_kernel<<<dim3(256), dim3(1024), 0, stream>>>(
        img_feat, img_loc, edge_src, edge_dst,
        W_img, b_img, W_loc, b_loc, W_rel, b_rel,
        out_node, out_edge, Wt_img, Wt_rel, proj, flags);
}

// Round 10
// 73.063 us; speedup vs baseline: 1.1177x; 1.1177x over previous
//
#include <hip/hip_runtime.h>
#include <hip/hip_bf16.h>
#include <stdint.h>

#define B_   32
#define N_   128
#define E_   8192
#define IMG_ 2048
#define H_   128

typedef __attribute__((ext_vector_type(8))) short bf16x8;
typedef __attribute__((ext_vector_type(4))) float f32x4;

__device__ inline uint16_t f2bf(float x) {
    uint32_t u = __float_as_uint(x);
    uint32_t r = (u + 0x7FFFu + ((u >> 16) & 1u)) >> 16;
    return (uint16_t)r;
}
__device__ inline float bf2f(short x) {
    return __uint_as_float(((uint32_t)(uint16_t)x) << 16);
}

// ---------------------------------------------------------------------------
// P: weight transpose+convert to bf16 k-major (r4 verbatim).
// ---------------------------------------------------------------------------
__global__ __launch_bounds__(256) void prep_kernel(
    const float* __restrict__ W_img, const float* __restrict__ W_rel,
    uint16_t* __restrict__ Wt_img, uint16_t* __restrict__ Wt_rel) {
    int bid = blockIdx.x, tid = threadIdx.x;
    if (bid < 32) {
        __shared__ float t[64][129];
        int k0 = bid * 64;
        const float* src = W_img + (size_t)k0 * H_;
        #pragma unroll
        for (int it = 0; it < 32; it++) {
            int idx = it * 256 + tid;            // 0..8191 over [64k][128c]
            t[idx >> 7][idx & 127] = src[idx];
        }
        __syncthreads();
        int c = tid >> 1, kh = (tid & 1) * 32;
        uint16_t* dst = Wt_img + (size_t)c * IMG_ + k0 + kh;
        #pragma unroll
        for (int j = 0; j < 32; j++) dst[j] = f2bf(t[kh + j][c]);
    } else {
        int t2 = (bid - 32) * 256 + tid;         // 0..32767
        int c = t2 >> 8, k = t2 & 255;
        Wt_rel[t2] = f2bf(W_rel[k * H_ + c]);
    }
}

// ---------------------------------------------------------------------------
// NODE+PROJ, 2-blocks/CU version. 512 blocks x 512 thr (8 waves); block =
// 8-row strip. A-tile = 8 rows x 2048 fp32 = 64 KB staged once (full K,
// global_load_lds, XOR-swizzled source). Waves = (4 K-slices of 512) x
// (2 col-halves of 64). MFMA uses 16x16x32 with A rows 8..15 duplicating
// 0..7 (stores guarded to rows<8). red[4][8][128] = 16 KB aliases the
// A-tile; imgb is a separate 2.2 KB buffer. Total LDS ~68 KB -> 2 blocks/CU
// so barrier phases of one block overlap compute of the other.
// ---------------------------------------------------------------------------
__global__ __launch_bounds__(512) void node_proj_kernel(
    const float* __restrict__ img_feat,
    const uint16_t* __restrict__ Wt_img,
    const uint16_t* __restrict__ Wt_rel,
    const float* __restrict__ img_loc,
    const float* __restrict__ b_img,
    const float* __restrict__ W_loc,
    const float* __restrict__ b_loc,
    const float* __restrict__ b_rel,
    float* __restrict__ out_node,
    uint16_t* __restrict__ proj) {
    __shared__ __align__(16) char lds_raw[65536];        // A-tile / red alias
    __shared__ __align__(16) uint16_t imgb[8][136];      // bf16 img strip

    int strip = blockIdx.x;          // 8-row strip, 0..511
    int tid = threadIdx.x;           // 0..511
    int w  = tid >> 6;               // wave 0..7
    int kw = w & 3;                  // K-slice (512 wide)
    int ch = w >> 2;                 // col half (64 cols)
    int l  = tid & 63;
    int lr = l & 15;
    int kq = l >> 4;
    int row8 = lr & 7;

    float (*red)[8][128] = (float (*)[8][128])lds_raw;   // [4][8][128] 16 KB

    // ---- stage A: 8 rows x 8 KB, linear LDS dest, swizzled source ----
    const char* gA = (const char*)(img_feat + (size_t)strip * 8 * IMG_);
    #pragma unroll
    for (int r = 0; r < 8; r++) {
        int L = r * 8192 + tid * 16;
        int row = L >> 13;                       // 0..7
        int koff = L & 8191;
        int gsrc = row * 8192 + (koff ^ (row << 4));
        __builtin_amdgcn_global_load_lds(
            (const __attribute__((address_space(1))) void*)(gA + gsrc),
            (__attribute__((address_space(3))) void*)(lds_raw + L), 16, 0, 0);
    }

    // ---- prefetch B for ks=0 ----
    int kbase = kw * 512 + kq * 8;
    const uint16_t* wbase = Wt_img + (size_t)(ch * 64) * IMG_;
    bf16x8 bcur[4];
    #pragma unroll
    for (int n = 0; n < 4; n++)
        bcur[n] = *(const bf16x8*)(wbase + (size_t)(n * 16 + lr) * IMG_ + kbase);

    __syncthreads();   // A-tile in LDS, bcur in regs

    // ---- GEMM: wave (kw,ch) covers K [kw*512,+512), cols [ch*64,+64) ----
    f32x4 acc[4];
    #pragma unroll
    for (int n = 0; n < 4; n++) acc[n] = (f32x4){0.f, 0.f, 0.f, 0.f};
    int sw = row8 << 4;
    #pragma unroll
    for (int ks = 0; ks < 16; ks++) {
        int koffb = kw * 2048 + ks * 128 + kq * 32;   // byte offset in row
        float4 a0 = *(const float4*)(lds_raw + row8 * 8192 + (koffb ^ sw));
        float4 a1 = *(const float4*)(lds_raw + row8 * 8192 + ((koffb + 16) ^ sw));
        bf16x8 bn[4];
        if (ks < 15) {
            int kn = kbase + (ks + 1) * 32;
            #pragma unroll
            for (int n = 0; n < 4; n++)
                bn[n] = *(const bf16x8*)(wbase + (size_t)(n * 16 + lr) * IMG_ + kn);
        }
        bf16x8 af;
        af[0] = (short)f2bf(a0.x); af[1] = (short)f2bf(a0.y);
        af[2] = (short)f2bf(a0.z); af[3] = (short)f2bf(a0.w);
        af[4] = (short)f2bf(a1.x); af[5] = (short)f2bf(a1.y);
        af[6] = (short)f2bf(a1.z); af[7] = (short)f2bf(a1.w);
        #pragma unroll
        for (int n = 0; n < 4; n++)
            acc[n] = __builtin_amdgcn_mfma_f32_16x16x32_bf16(af, bcur[n], acc[n], 0, 0, 0);
        if (ks < 15) {
            #pragma unroll
            for (int n = 0; n < 4; n++) bcur[n] = bn[n];
        }
    }
    __syncthreads();   // all A-tile reads done before red overwrites it

    // ---- dump partials (rows 0..7 live in lanes kq<2) ----
    if (kq < 2) {
        #pragma unroll
        for (int n = 0; n < 4; n++)
            #pragma unroll
            for (int r = 0; r < 4; r++)
                red[kw][kq * 4 + r][ch * 64 + n * 16 + lr] = acc[n][r];
    }
    __syncthreads();

    // ---- reduce (4 partials) + epilogue: 2 cells/thread ----
    int col = tid & 127;
    int row0 = tid >> 7;          // 0..3
    int row1 = row0 + 4;
    float s0 = 0.f, s1 = 0.f;
    #pragma unroll
    for (int p = 0; p < 4; p++) {
        s0 += red[p][row0][col];
        s1 += red[p][row1][col];
    }
    {
        float bi = b_img[col];
        float bl = b_loc[col];
        float wl[5];
        #pragma unroll
        for (int j = 0; j < 5; j++) wl[j] = W_loc[j * H_ + col];
        float img0 = s0 + bi, img1 = s1 + bi;
        int g0 = strip * 8 + row0, g1 = strip * 8 + row1;
        const float* lc0 = img_loc + g0 * 5;
        const float* lc1 = img_loc + g1 * 5;
        float loc0 = bl, loc1 = bl;
        #pragma unroll
        for (int j = 0; j < 5; j++) { loc0 += lc0[j] * wl[j]; loc1 += lc1[j] * wl[j]; }
        out_node[(size_t)g0 * H_ + col] = img0 + loc0;
        out_node[(size_t)g1 * H_ + col] = img1 + loc1;
        imgb[row0][col] = f2bf(img0);
        imgb[row1][col] = f2bf(img1);
    }
    __syncthreads();   // imgb visible

    // ---- proj GEMM: wave w -> cols w*32 + {lr, 16+lr}; K=128 ----
    {
        int kl = kq * 8;
        int cp0 = w * 32 + lr;
        int cp1 = cp0 + 16;
        const uint16_t* bb0 = (cp0 < 128)
            ? (Wt_rel + (size_t)cp0 * 256)
            : (Wt_rel + (size_t)(cp0 - 128) * 256 + 128);
        const uint16_t* bb1 = (cp1 < 128)
            ? (Wt_rel + (size_t)cp1 * 256)
            : (Wt_rel + (size_t)(cp1 - 128) * 256 + 128);
        f32x4 p0 = (f32x4){0.f, 0.f, 0.f, 0.f};
        f32x4 p1 = p0;
        #pragma unroll
        for (int ks = 0; ks < 4; ks++) {
            int k = ks * 32 + kl;
            bf16x8 af = *(const bf16x8*)(&imgb[row8][k]);
            bf16x8 bf0 = *(const bf16x8*)(bb0 + k);
            bf16x8 bf1 = *(const bf16x8*)(bb1 + k);
            p0 = __builtin_amdgcn_mfma_f32_16x16x32_bf16(af, bf0, p0, 0, 0, 0);
            p1 = __builtin_amdgcn_mfma_f32_16x16x32_bf16(af, bf1, p1, 0, 0, 0);
        }
        float br0 = (cp0 < 128) ? b_rel[cp0] : 0.f;
        float br1 = (cp1 < 128) ? b_rel[cp1] : 0.f;
        if (kq < 2) {
            #pragma unroll
            for (int r = 0; r < 4; r++) {
                int grow = strip * 8 + kq * 4 + r;
                proj[(size_t)grow * 256 + cp0] = f2bf(p0[r] + br0);
                proj[(size_t)grow * 256 + cp1] = f2bf(p1[r] + br1);
            }
        }
    }
}

// ---------------------------------------------------------------------------
// EDGE stream (r4 verbatim): hoisted indices, 4-deep gather staging,
// plain cached coalesced float4 stores.
// ---------------------------------------------------------------------------
__global__ __launch_bounds__(256) void edge_kernel(
    const uint16_t* __restrict__ proj,
    const int* __restrict__ edge_src,
    const int* __restrict__ edge_dst,
    float* __restrict__ out_edge) {
    int t = blockIdx.x * 256 + threadIdx.x;   // 0..524287
    int b0 = t >> 17;                         // 0..3
    int r  = t & 131071;
    int e  = r >> 4;
    int c  = (r & 15) * 8;
    int s  = edge_src[e];
    int d  = edge_dst[e];
    const uint16_t* ps = proj + ((size_t)(b0 * N_ + s) * 256 + c);
    const uint16_t* pd = proj + ((size_t)(b0 * N_ + d) * 256 + 128 + c);
    float* op = out_edge + ((size_t)(b0 * E_ + e) * H_ + c);
    const size_t PSTR = (size_t)4 * N_ * 256;      // proj elems per 4 batches
    const size_t OSTR = (size_t)4 * E_ * H_;       // out floats per 4 batches

    #pragma unroll
    for (int h = 0; h < 2; h++) {
        bf16x8 av[4], bv[4];
        #pragma unroll
        for (int i = 0; i < 4; i++) {
            size_t it = (size_t)(h * 4 + i);
            av[i] = *(const bf16x8*)(ps + it * PSTR);
            bv[i] = *(const bf16x8*)(pd + it * PSTR);
        }
        #pragma unroll
        for (int i = 0; i < 4; i++) {
            size_t it = (size_t)(h * 4 + i);
            float4 o0, o1;
            o0.x = bf2f(av[i][0]) + bf2f(bv[i][0]);
            o0.y = bf2f(av[i][1]) + bf2f(bv[i][1]);
            o0.z = bf2f(av[i][2]) + bf2f(bv[i][2]);
            o0.w = bf2f(av[i][3]) + bf2f(bv[i][3]);
            o1.x = bf2f(av[i][4]) + bf2f(bv[i][4]);
            o1.y = bf2f(av[i][5]) + bf2f(bv[i][5]);
            o1.z = bf2f(av[i][6]) + bf2f(bv[i][6]);
            o1.w = bf2f(av[i][7]) + bf2f(bv[i][7]);
            float* dst = op + it * OSTR;
            *(float4*)dst = o0;
            *(float4*)(dst + 4) = o1;
        }
    }
}

// ---------------------------------------------------------------------------
extern "C" void kernel_launch(void* const* d_in, const int* in_sizes, int n_in,
                              void* d_out, int out_size, void* d_ws, size_t ws_size,
                              hipStream_t stream) {
    const float* img_feat = (const float*)d_in[0];
    const float* img_loc  = (const float*)d_in[1];
    const int*   edge_src = (const int*)d_in[2];
    const int*   edge_dst = (const int*)d_in[3];
    const float* W_img    = (const float*)d_in[4];
    const float* b_img    = (const float*)d_in[5];
    const float* W_loc    = (const float*)d_in[6];
    const float* b_loc    = (const float*)d_in[7];
    const float* W_rel    = (const float*)d_in[8];
    const float* b_rel    = (const float*)d_in[9];

    float* out_node = (float*)d_out;                       // [B,N,H]
    float* out_edge = out_node + (size_t)B_ * N_ * H_;     // [B,E,H]

    char* ws = (char*)d_ws;
    uint16_t* Wt_img = (uint16_t*)ws;                      // 512 KB
    uint16_t* Wt_rel = (uint16_t*)(ws + 524288);           // 64 KB
    uint16_t* proj   = (uint16_t*)(ws + 524288 + 65536);   // 2 MB [4096][256]

    prep_kernel<<<dim3(160), dim3(256), 0, stream>>>(W_img, W_rel, Wt_img, Wt_rel);

    node_proj_kernel<<<dim3(512), dim3(512), 0, stream>>>(
        img_feat, Wt_img, Wt_rel, img_loc, b_img, W_loc, b_loc, b_rel,
        out_node, proj);

    edge_kernel<<<dim3(2048), dim3(256), 0, stream>>>(
        proj, edge_src, edge_dst, out_edge);
}